// Round 13
// baseline (1401.330 us; speedup 1.0000x reference)
//
#include <hip/hip_runtime.h>
#include <hip/hip_bf16.h>
#include <stdint.h>

typedef __attribute__((ext_vector_type(4))) float f32x4;
typedef __attribute__((ext_vector_type(8))) short s16x8;
typedef __attribute__((ext_vector_type(2))) unsigned int u32x2;
typedef __attribute__((ext_vector_type(4))) unsigned int u32x4;

#define V_N   50000
#define T_N   512
#define B_N   256
#define E_N   300
#define H_N   256

#define L2E     1.44269504088896f
#define TWO_L2E 2.88539008177793f

// ---- workspace layout (bytes) ----
#define OFF_ZE    0ULL              // zE bf16 [50000][2048]  (permuted cols, fw|bw), bias+log2e folded
#define OFF_EMBP  204800000ULL      // emb padded bf16 [50000][320]
#define OFF_WCT   236800000ULL      // WcatT bf16 [2048][320]
#define OFF_JF    238110720ULL      // j-gate bf16 fragments (x 2*log2e)
#define OFF_IFOF  238372864ULL      // i/f/o fp8 fragments (x -log2e*32)
#define OFF_LEN   238766080ULL      // lengths int32 [256]
#define OFF_HFIN  238767104ULL      // final h f32 [2][256][256]
#define WS_NEED   239291392ULL

#if __has_builtin(__builtin_amdgcn_exp2f)
#define EXP2F(x) __builtin_amdgcn_exp2f(x)
#else
#define EXP2F(x) exp2f(x)
#endif
#define RCPF(x) __builtin_amdgcn_rcpf(x)

__device__ __forceinline__ unsigned short f2bf(float f) {
  union { float f; unsigned int u; } v; v.f = f;
  unsigned int r = v.u + 0x7FFFu + ((v.u >> 16) & 1u);
  return (unsigned short)(r >> 16);
}
__device__ __forceinline__ float bf2f(unsigned int b16) {
  union { unsigned int u; float f; } v; v.u = b16 << 16;
  return v.f;
}
__device__ __forceinline__ f32x4 mfma_bf16f(s16x8 a, s16x8 b, f32x4 c) {
  return __builtin_amdgcn_mfma_f32_16x16x32_bf16(a, b, c, 0, 0, 0);
}
__device__ __forceinline__ f32x4 mfma_fp8f(long a, long b, f32x4 c) {
  return __builtin_amdgcn_mfma_f32_16x16x32_fp8_fp8(a, b, c, 0, 0, 0);
}

// ---------------- lengths ----------------
__global__ __launch_bounds__(64) void k_lengths(const int* __restrict__ ids, char* __restrict__ ws) {
  const int row = blockIdx.x, l = threadIdx.x;
  int c = 0;
  #pragma unroll
  for (int j = 0; j < 8; ++j) c += (ids[row * T_N + l + 64 * j] != 0) ? 1 : 0;
  #pragma unroll
  for (int off = 32; off; off >>= 1) c += __shfl_down(c, off);
  if (l == 0) *(int*)(ws + OFF_LEN + row * 4) = c;
}

// ---------------- embedding -> bf16, K padded 300->320 ----------------
__global__ __launch_bounds__(320) void k_embpad(const float* __restrict__ emb, char* __restrict__ ws) {
  const int row = blockIdx.x, k = threadIdx.x;
  unsigned short v = (k < 300) ? f2bf(emb[(size_t)row * 300 + k]) : (unsigned short)0;
  ((unsigned short*)(ws + OFF_EMBP))[(size_t)row * 320 + k] = v;
}

// ------- x-part weights, transposed+permuted, log2e-scaled per gate -------
__global__ __launch_bounds__(320) void k_wcat(const float* __restrict__ Wfw, const float* __restrict__ Wbw,
                                              char* __restrict__ ws) {
  const int p = blockIdx.x, k = threadIdx.x;
  const int dir = p >> 10, pp = p & 1023;
  const int w8 = pp >> 7, i5 = (pp >> 2) & 31, gt = pp & 3;
  const int n = w8 * 32 + i5, col = gt * 256 + n;
  const float sc = (gt == 1) ? TWO_L2E : -L2E;
  const float* W = dir ? Wbw : Wfw;
  unsigned short v = (k < 300) ? f2bf(W[(size_t)k * 1024 + col] * sc) : (unsigned short)0;
  ((unsigned short*)(ws + OFF_WCT))[(size_t)p * 320 + k] = v;
}

// ---------------- j-gate W_h fragments (bf16, x 2*log2e) ----------------
__global__ __launch_bounds__(512) void k_jfrag(const float* __restrict__ Wfw, const float* __restrict__ Wbw,
                                               char* __restrict__ ws) {
  const int f = blockIdx.x * 512 + threadIdx.x;
  const int j = f & 7, l = (f >> 3) & 63, s = (f >> 9) & 7;
  const int q = (f >> 12) & 1, w = (f >> 13) & 7, dir = (f >> 16) & 1;
  const int n = 32 * w + 16 * q + (l & 15);
  const int k = 32 * s + 8 * (l >> 4) + j;
  const float* W = dir ? Wbw : Wfw;
  ((unsigned short*)(ws + OFF_JF))[f] = f2bf(W[(size_t)(300 + k) * 1024 + 256 + n] * TWO_L2E);
}

// ---------------- i/f/o W_h fragments (fp8 e4m3, x -log2e*32) ----------------
__global__ __launch_bounds__(512) void k_ifofrag(const float* __restrict__ Wfw, const float* __restrict__ Wbw,
                                                 char* __restrict__ ws) {
  const int f = blockIdx.x * 512 + threadIdx.x;
  const int g3 = f >> 17;
  const int r = f & 131071;
  const int j = r & 7, l = (r >> 3) & 63, s = (r >> 9) & 7;
  const int q = (r >> 12) & 1, w = (r >> 13) & 7, dir = (r >> 16) & 1;
  const int gate = (g3 == 0) ? 0 : ((g3 == 1) ? 2 : 3);
  const int n = 32 * w + 16 * q + (l & 15);
  const int k = 32 * s + 8 * (l >> 4) + j;
  const float* W = dir ? Wbw : Wfw;
  const float v = W[(size_t)(300 + k) * 1024 + gate * 256 + n] * (-L2E * 32.f);
  const int pk = __builtin_amdgcn_cvt_pk_fp8_f32(v, v, 0, false);
  ((unsigned char*)(ws + OFF_IFOF))[f] = (unsigned char)(pk & 0xFF);
}

// ---------------- zE = emb_pad @ WcatT^T + bias (scaled) ----------------
__global__ __launch_bounds__(512) void k_zegemm(char* __restrict__ ws, const float* __restrict__ bfw,
                                                const float* __restrict__ bbw) {
  const int tid = threadIdx.x;
  const int l = tid & 63, w = tid >> 6;
  const int l15 = l & 15, lq = l >> 4;
  const int wr = w >> 2, wc = w & 3;
  const int mbase = blockIdx.x * 128;
  const int nbase = blockIdx.y * 256;
  __shared__ char lds[24576];
  const unsigned short* Ab = (const unsigned short*)(ws + OFF_EMBP);
  const unsigned short* Bb = (const unsigned short*)(ws + OFF_WCT);
  unsigned short* Cb = (unsigned short*)(ws + OFF_ZE);
  const f32x4 zero4 = {0.f, 0.f, 0.f, 0.f};
  f32x4 acc[4][4];
  #pragma unroll
  for (int a = 0; a < 4; ++a)
    #pragma unroll
    for (int b = 0; b < 4; ++b) acc[a][b] = zero4;

  for (int kk = 0; kk < 320; kk += 32) {
    if (kk) __syncthreads();
    {
      const int row = tid >> 2, sl = tid & 3;
      const int gm = mbase + row;
      s16x8 v = {0, 0, 0, 0, 0, 0, 0, 0};
      if (gm < V_N) v = *(const s16x8*)(Ab + (size_t)gm * 320 + kk + sl * 8);
      *(s16x8*)(lds + row * 64 + ((sl ^ ((row >> 1) & 3)) << 4)) = v;
    }
    {
      const int col = tid >> 1, hf = tid & 1;
      #pragma unroll
      for (int ss = 0; ss < 2; ++ss) {
        const int sl = 2 * hf + ss;
        s16x8 v = *(const s16x8*)(Bb + (size_t)(nbase + col) * 320 + kk + sl * 8);
        *(s16x8*)(lds + 8192 + col * 64 + ((sl ^ ((col >> 1) & 3)) << 4)) = v;
      }
    }
    __syncthreads();
    s16x8 af[4], bfr[4];
    #pragma unroll
    for (int mi = 0; mi < 4; ++mi) {
      const int row = 64 * wr + 16 * mi + l15;
      af[mi] = *(const s16x8*)(lds + row * 64 + ((lq ^ ((row >> 1) & 3)) << 4));
    }
    #pragma unroll
    for (int ni = 0; ni < 4; ++ni) {
      const int col = 64 * wc + 16 * ni + l15;
      bfr[ni] = *(const s16x8*)(lds + 8192 + col * 64 + ((lq ^ ((col >> 1) & 3)) << 4));
    }
    #pragma unroll
    for (int mi = 0; mi < 4; ++mi)
      #pragma unroll
      for (int ni = 0; ni < 4; ++ni)
        acc[mi][ni] = mfma_bf16f(af[mi], bfr[ni], acc[mi][ni]);
  }
  float bcol[4];
  #pragma unroll
  for (int ni = 0; ni < 4; ++ni) {
    const int colp = nbase + 64 * wc + 16 * ni + l15;
    const int dirc = colp >> 10, pp = colp & 1023;
    const int gt = pp & 3;
    const int n = ((pp >> 7) << 5) + ((pp >> 2) & 31);
    const float* bsel = dirc ? bbw : bfw;
    const float bv = bsel[gt * 256 + n];
    bcol[ni] = (gt == 1) ? bv * TWO_L2E : -(bv + ((gt == 2) ? 1.f : 0.f)) * L2E;
  }
  #pragma unroll
  for (int mi = 0; mi < 4; ++mi)
    #pragma unroll
    for (int ni = 0; ni < 4; ++ni)
      #pragma unroll
      for (int rr = 0; rr < 4; ++rr) {
        const int gr = mbase + 64 * wr + 16 * mi + 4 * lq + rr;
        if (gr < V_N)
          Cb[(size_t)gr * 2048 + nbase + 64 * wc + 16 * ni + l15] = f2bf(acc[mi][ni][rr] + bcol[ni]);
      }
}

// ---------------- bidirectional LSTM recurrence ----------------
// 8 waves, q-sequential MFMA; q=1 j-weights (WJ1) AND q=1 i-gate fp8 weights (WF1) in
// per-wave-private LDS -> resident MFMA regs = 112 + 16 acc = 128 AGPR; total live <= 256.
// LDS: idt u16[512][16] 16K | h bf16 dbuf 2x8K | h fp8 dbuf 2x4K | WJ1 64K | WF1 32K = 136K
#define L_IDT  0
#define L_HB0  16384
#define L_HB1  24576
#define L_HF0  32768
#define L_HF1  36864
#define L_WJ1  40960
#define L_WF1  106496
#define L_LDS  139264

#define LSTM_STEP(CUR, S)                                                          \
  do {                                                                             \
    const int tt_ = dir ? (T_N - 1 - (S)) : (S);                                   \
    const char* hb_  = lds + ((CUR) ? L_HB1 : L_HB0);                              \
    const char* hf8_ = lds + ((CUR) ? L_HF1 : L_HF0);                              \
    char* hbn_  = lds + ((CUR) ? L_HB0 : L_HB1);                                   \
    char* hf8n_ = lds + ((CUR) ? L_HF0 : L_HF1);                                   \
    _Pragma("unroll")                                                              \
    for (int q = 0; q < 2; ++q) {                                                  \
      f32x4 aI_ = zero4, aJ_ = zero4, aF_ = zero4, aO_ = zero4;                    \
      _Pragma("unroll")                                                            \
      for (int s8 = 0; s8 < 8; ++s8) {                                             \
        const int slot = 4 * s8 + lq;                                              \
        s16x8 abf = *(const s16x8*)(hb_ + l15 * 512 + ((slot ^ l15) << 4));        \
        long af8  = *(const long*)(hf8_ + l15 * 256 + ((slot ^ l15) << 3));        \
        s16x8 bj = (q == 0) ? WJ0[s8] : *(const s16x8*)(wj1b + (s8 << 10));        \
        long bi  = (q == 0) ? WI0[s8] : *(const long*)(wf1b + (s8 << 9));          \
        aJ_ = mfma_bf16f(abf, bj, aJ_);                                            \
        aI_ = mfma_fp8f(af8, bi, aI_);                                             \
        aF_ = mfma_fp8f(af8, WFO[0][q][s8], aF_);                                  \
        aO_ = mfma_fp8f(af8, WFO[1][q][s8], aO_);                                  \
      }                                                                            \
      _Pragma("unroll")                                                            \
      for (int r = 0; r < 4; ++r) {                                                \
        const int row = 4 * lq + r;                                                \
        const bool m_ = (tt_ < lenr[r]);                                           \
        const u32x2 zraw = zxr[q][r];                                              \
        const float zxi = bf2f(zraw.x & 0xFFFFu);                                  \
        const float zxj = bf2f(zraw.x >> 16);                                      \
        const float zxf = bf2f(zraw.y & 0xFFFFu);                                  \
        const float zxo = bf2f(zraw.y >> 16);                                      \
        const float zi = __builtin_fmaf(aI_[r], 0.0009765625f, zxi);               \
        const float zj = aJ_[r] + zxj;                                             \
        const float zf = __builtin_fmaf(aF_[r], 0.0009765625f, zxf);               \
        const float zo = __builtin_fmaf(aO_[r], 0.0009765625f, zxo);               \
        const float vi = EXP2F(zi);                                                \
        const float uj = EXP2F(zj);                                                \
        const float vf = EXP2F(zf);                                                \
        const float sfg = RCPF(1.f + vf);                                          \
        const float tij = (uj - 1.f) * RCPF((1.f + vi) * (1.f + uj));              \
        const float cn = __builtin_fmaf(cst[r + 4 * q], sfg, tij);                 \
        const float cne = fminf(cn, 30.f);                                         \
        const float wv = EXP2F(cne * TWO_L2E);                                     \
        const float xo = EXP2F(zo);                                                \
        const float hn = (wv - 1.f) * RCPF((wv + 1.f) * (1.f + xo));               \
        cst[r + 4 * q] = m_ ? cn : cst[r + 4 * q];                                 \
        const float hold = bf2f(q ? (hp[r] >> 16) : (hp[r] & 0xFFFFu));            \
        const float hv = m_ ? hn : hold;                                           \
        unsigned int pkb;                                                          \
        asm("v_cvt_pk_bf16_f32 %0, %1, %2" : "=v"(pkb) : "v"(hv), "v"(hv));        \
        pkb &= 0xFFFFu;                                                            \
        hp[r] = q ? ((hp[r] & 0xFFFFu) | (pkb << 16)) : ((hp[r] & 0xFFFF0000u) | pkb); \
        const int n0q = 32 * w + 16 * q + l15;                                     \
        *(unsigned short*)(hbn_ + row * 512 + (((n0q >> 3) ^ row) << 4) + ((n0q & 7) << 1)) = (unsigned short)pkb; \
        const int pk8 = __builtin_amdgcn_cvt_pk_fp8_f32(hv * 32.f, hv * 32.f, 0, false); \
        hf8n_[row * 256 + (((n0q >> 3) ^ row) << 3) + (n0q & 7)] = (char)(pk8 & 0xFF); \
      }                                                                            \
      if ((S) + 1 < T_N) { /* refill zxr[q] for step S+1 (just freed; ample cover) */ \
        const unsigned short* idt_ = (const unsigned short*)(lds + L_IDT) + ((S) + 1) * 16 + 4 * lq; \
        const u32x2 idp = *(const u32x2*)(idt_);                                   \
        const unsigned int idv0 = idp.x & 0xFFFFu, idv1 = idp.x >> 16;             \
        const unsigned int idv2 = idp.y & 0xFFFFu, idv3 = idp.y >> 16;             \
        const int lofs = (w << 8) + (q << 7) + (l15 << 3);                         \
        zxr[q][0] = *(const u32x2*)(zebd + ((size_t)idv0 << 12) + lofs);           \
        zxr[q][1] = *(const u32x2*)(zebd + ((size_t)idv1 << 12) + lofs);           \
        zxr[q][2] = *(const u32x2*)(zebd + ((size_t)idv2 << 12) + lofs);           \
        zxr[q][3] = *(const u32x2*)(zebd + ((size_t)idv3 << 12) + lofs);           \
      }                                                                            \
      __builtin_amdgcn_sched_barrier(0);  /* keep q-phases separate: 16-AGPR acc live range */ \
    }                                                                              \
    asm volatile("s_waitcnt lgkmcnt(0)" ::: "memory");                             \
    __builtin_amdgcn_s_barrier();                                                  \
    asm volatile("" ::: "memory");                                                 \
  } while (0)

__global__ __launch_bounds__(512, 1) void k_lstm(const int* __restrict__ ids, char* __restrict__ ws) {
  const int tid = threadIdx.x;
  const int l = tid & 63, w = tid >> 6;
  const int l15 = l & 15, lq = l >> 4;
  const int bid = blockIdx.x;
  const int dir = bid & 1, g = bid >> 1;

  __shared__ char lds[L_LDS];

  { // one-time id table idt[sidx][row] u16 (dir-reversed step index)
    unsigned short* idt = (unsigned short*)(lds + L_IDT);
    const int row = tid & 15;
    const int tb = (tid >> 4) * 16;
    const int base = (g * 16 + row) * T_N;
    #pragma unroll 4
    for (int i = 0; i < 16; ++i) {
      const int t = tb + i;
      const int id = ids[base + t];
      const int sidx = dir ? (T_N - 1 - t) : t;
      idt[sidx * 16 + row] = (unsigned short)id;
    }
  }
  { // zero h buf0
    unsigned int* p = (unsigned int*)(lds + L_HB0);
    #pragma unroll
    for (int i = 0; i < 4; ++i) p[tid + 512 * i] = 0u;
    unsigned int* p2 = (unsigned int*)(lds + L_HF0);
    #pragma unroll
    for (int i = 0; i < 2; ++i) p2[tid + 512 * i] = 0u;
  }
  { // stage q=1 j-weights (bf16) and q=1 i-gate weights (fp8) into per-wave LDS
    const char* jf = ws + OFF_JF;
    #pragma unroll
    for (int s = 0; s < 8; ++s) {
      s16x8 v = *(const s16x8*)(jf + (size_t)((((dir * 8 + w) * 2 + 1) * 8 + s) * 64 + l) * 16);
      *(s16x8*)(lds + L_WJ1 + (w << 13) + (s << 10) + (l << 4)) = v;
    }
    const char* ff = ws + OFF_IFOF;
    #pragma unroll
    for (int s = 0; s < 8; ++s) {
      long v = *(const long*)(ff + (dir << 16) + (w << 13) + (1 << 12) + (s << 9) + (l << 3));
      *(long*)(lds + L_WF1 + (w << 12) + (s << 9) + (l << 3)) = v;
    }
  }

  // resident weight fragments: WJ0 32 + WI0 16 + WFO 64 = 112 regs (+16 acc = 128 AGPR)
  s16x8 WJ0[8];
  long WI0[8];
  long WFO[2][2][8];
  {
    const char* jf = ws + OFF_JF;
    #pragma unroll
    for (int s = 0; s < 8; ++s)
      WJ0[s] = *(const s16x8*)(jf + (size_t)((((dir * 8 + w) * 2 + 0) * 8 + s) * 64 + l) * 16);
    const char* ff = ws + OFF_IFOF;
    #pragma unroll
    for (int s = 0; s < 8; ++s)
      WI0[s] = *(const long*)(ff + (dir << 16) + (w << 13) + (0 << 12) + (s << 9) + (l << 3));
    #pragma unroll
    for (int g2 = 0; g2 < 2; ++g2)
      #pragma unroll
      for (int q = 0; q < 2; ++q)
        #pragma unroll
        for (int s = 0; s < 8; ++s)
          WFO[g2][q][s] = *(const long*)(ff + (g2 + 1) * 131072 + (dir << 16) + (w << 13) + (q << 12) + (s << 9) + (l << 3));
  }
  int lenr[4];
  {
    const int* lp = (const int*)(ws + OFF_LEN);
    #pragma unroll
    for (int r = 0; r < 4; ++r) lenr[r] = lp[g * 16 + 4 * lq + r];
  }
  float cst[8] = {0, 0, 0, 0, 0, 0, 0, 0};
  unsigned int hp[4] = {0, 0, 0, 0};      // packed bf16 h (q0 | q1<<16) per r
  const char* zebd = (const char*)ws + OFF_ZE + (dir << 11);
  const char* wj1b = lds + L_WJ1 + (w << 13) + (l << 4);   // per-thread q1 j-frag base
  const char* wf1b = lds + L_WF1 + (w << 12) + (l << 3);   // per-thread q1 i-frag base
  const f32x4 zero4 = {0.f, 0.f, 0.f, 0.f};
  u32x2 zxr[2][4];                         // this lane's zx slice for the current step

  __syncthreads();                 // idt + h0 + WJ1/WF1 ready

  { // prologue: zx for step 0 (both q halves)
    const unsigned short* idt0 = (const unsigned short*)(lds + L_IDT) + 4 * lq;
    const u32x2 idp = *(const u32x2*)(idt0);
    const unsigned int idv[4] = { idp.x & 0xFFFFu, idp.x >> 16, idp.y & 0xFFFFu, idp.y >> 16 };
    #pragma unroll
    for (int r = 0; r < 4; ++r) {
      const char* gb = zebd + ((size_t)idv[r] << 12) + (w << 8) + (l15 << 3);
      zxr[0][r] = *(const u32x2*)(gb);
      zxr[1][r] = *(const u32x2*)(gb + 128);
    }
  }

  for (int s = 0; s < T_N; s += 2) {
    LSTM_STEP(0, s);
    LSTM_STEP(1, s + 1);
  }

  float* hout = (float*)(ws + OFF_HFIN) + (size_t)dir * 65536;
  #pragma unroll
  for (int r = 0; r < 4; ++r) {
    const int grow = (g * 16 + 4 * lq + r) * 256 + 32 * w + l15;
    hout[grow]      = bf2f(hp[r] & 0xFFFFu);
    hout[grow + 16] = bf2f(hp[r] >> 16);
  }
}

// ---------------- output projection ----------------
__global__ __launch_bounds__(64) void k_scores(const char* __restrict__ ws, const float* __restrict__ Wout,
                                               const float* __restrict__ bout, float* __restrict__ out) {
  const int row = blockIdx.x, l = threadIdx.x;
  const float* h1 = (const float*)(ws + OFF_HFIN);
  const float* h2 = h1 + 65536;
  float a0 = 0.f, a1 = 0.f;
  #pragma unroll
  for (int j = 0; j < 8; ++j) {
    const int k = l + 64 * j;
    const float v = (k < 256) ? h1[row * 256 + k] : h2[row * 256 + (k - 256)];
    a0 += v * Wout[2 * k];
    a1 += v * Wout[2 * k + 1];
  }
  #pragma unroll
  for (int off = 32; off; off >>= 1) {
    a0 += __shfl_down(a0, off);
    a1 += __shfl_down(a1, off);
  }
  if (l == 0) {
    out[2 * row] = a0 + bout[0];
    out[2 * row + 1] = a1 + bout[1];
  }
}

__global__ void k_sentinel(float* out) { out[threadIdx.x] = -12345.f; }

extern "C" void kernel_launch(void* const* d_in, const int* in_sizes, int n_in,
                              void* d_out, int out_size, void* d_ws, size_t ws_size,
                              hipStream_t stream) {
  const int* ids = (const int*)d_in[0];
  const float* emb = (const float*)d_in[1];
  const float* Wfw = (const float*)d_in[2];
  const float* bfw = (const float*)d_in[3];
  const float* Wbw = (const float*)d_in[4];
  const float* bbw = (const float*)d_in[5];
  const float* Wout = (const float*)d_in[6];
  const float* bout = (const float*)d_in[7];
  float* out = (float*)d_out;
  char* ws = (char*)d_ws;
  (void)in_sizes; (void)n_in; (void)out_size;

  if (ws_size < WS_NEED) {
    k_sentinel<<<dim3(1), dim3(512), 0, stream>>>(out);
    return;
  }
  k_lengths<<<dim3(256), dim3(64), 0, stream>>>(ids, ws);
  k_embpad<<<dim3(50000), dim3(320), 0, stream>>>(emb, ws);
  k_wcat<<<dim3(2048), dim3(320), 0, stream>>>(Wfw, Wbw, ws);
  k_jfrag<<<dim3(256), dim3(512), 0, stream>>>(Wfw, Wbw, ws);
  k_ifofrag<<<dim3(768), dim3(512), 0, stream>>>(Wfw, Wbw, ws);
  k_zegemm<<<dim3(391, 8), dim3(512), 0, stream>>>(ws, bfw, bbw);
  k_lstm<<<dim3(32), dim3(512), 0, stream>>>(ids, ws);
  k_scores<<<dim3(256), dim3(64), 0, stream>>>(ws, Wout, bout, out);
}

// Round 14
// 1323.172 us; speedup vs baseline: 1.0591x; 1.0591x over previous
//
#include <hip/hip_runtime.h>
#include <hip/hip_bf16.h>
#include <stdint.h>

typedef __attribute__((ext_vector_type(4))) float f32x4;
typedef __attribute__((ext_vector_type(8))) short s16x8;
typedef __attribute__((ext_vector_type(2))) unsigned int u32x2;
typedef __attribute__((ext_vector_type(4))) unsigned int u32x4;

#define V_N   50000
#define T_N   512
#define B_N   256
#define E_N   300
#define H_N   256

#define L2E     1.44269504088896f
#define TWO_L2E 2.88539008177793f

// ---- workspace layout (bytes) ----
#define OFF_ZE    0ULL              // zE bf16 [50000][2048]  (permuted cols, fw|bw), bias+log2e folded
#define OFF_EMBP  204800000ULL      // emb padded bf16 [50000][320]
#define OFF_WCT   236800000ULL      // WcatT bf16 [2048][320]
#define OFF_JF    238110720ULL      // j-gate bf16 fragments (x 2*log2e)
#define OFF_IFOF  238372864ULL      // i/f/o fp8 fragments (x -log2e*32)
#define OFF_LEN   238766080ULL      // lengths int32 [256]
#define OFF_HFIN  238767104ULL      // final h f32 [2][256][256]
#define WS_NEED   239291392ULL

#if __has_builtin(__builtin_amdgcn_exp2f)
#define EXP2F(x) __builtin_amdgcn_exp2f(x)
#else
#define EXP2F(x) exp2f(x)
#endif
#define RCPF(x) __builtin_amdgcn_rcpf(x)

__device__ __forceinline__ unsigned short f2bf(float f) {
  union { float f; unsigned int u; } v; v.f = f;
  unsigned int r = v.u + 0x7FFFu + ((v.u >> 16) & 1u);
  return (unsigned short)(r >> 16);
}
__device__ __forceinline__ float bf2f(unsigned int b16) {
  union { unsigned int u; float f; } v; v.u = b16 << 16;
  return v.f;
}
__device__ __forceinline__ float asf(unsigned int u) {
  union { unsigned int u; float f; } v; v.u = u; return v.f;
}
__device__ __forceinline__ f32x4 mfma_bf16f(s16x8 a, s16x8 b, f32x4 c) {
  return __builtin_amdgcn_mfma_f32_16x16x32_bf16(a, b, c, 0, 0, 0);
}
__device__ __forceinline__ f32x4 mfma_fp8f(long a, long b, f32x4 c) {
  return __builtin_amdgcn_mfma_f32_16x16x32_fp8_fp8(a, b, c, 0, 0, 0);
}

// ---------------- lengths ----------------
__global__ __launch_bounds__(64) void k_lengths(const int* __restrict__ ids, char* __restrict__ ws) {
  const int row = blockIdx.x, l = threadIdx.x;
  int c = 0;
  #pragma unroll
  for (int j = 0; j < 8; ++j) c += (ids[row * T_N + l + 64 * j] != 0) ? 1 : 0;
  #pragma unroll
  for (int off = 32; off; off >>= 1) c += __shfl_down(c, off);
  if (l == 0) *(int*)(ws + OFF_LEN + row * 4) = c;
}

// ---------------- embedding -> bf16, K padded 300->320 ----------------
__global__ __launch_bounds__(320) void k_embpad(const float* __restrict__ emb, char* __restrict__ ws) {
  const int row = blockIdx.x, k = threadIdx.x;
  unsigned short v = (k < 300) ? f2bf(emb[(size_t)row * 300 + k]) : (unsigned short)0;
  ((unsigned short*)(ws + OFF_EMBP))[(size_t)row * 320 + k] = v;
}

// ------- x-part weights, transposed+permuted, log2e-scaled per gate -------
__global__ __launch_bounds__(320) void k_wcat(const float* __restrict__ Wfw, const float* __restrict__ Wbw,
                                              char* __restrict__ ws) {
  const int p = blockIdx.x, k = threadIdx.x;
  const int dir = p >> 10, pp = p & 1023;
  const int w8 = pp >> 7, i5 = (pp >> 2) & 31, gt = pp & 3;
  const int n = w8 * 32 + i5, col = gt * 256 + n;
  const float sc = (gt == 1) ? TWO_L2E : -L2E;
  const float* W = dir ? Wbw : Wfw;
  unsigned short v = (k < 300) ? f2bf(W[(size_t)k * 1024 + col] * sc) : (unsigned short)0;
  ((unsigned short*)(ws + OFF_WCT))[(size_t)p * 320 + k] = v;
}

// ---------------- j-gate W_h fragments (bf16, x 2*log2e) ----------------
__global__ __launch_bounds__(512) void k_jfrag(const float* __restrict__ Wfw, const float* __restrict__ Wbw,
                                               char* __restrict__ ws) {
  const int f = blockIdx.x * 512 + threadIdx.x;
  const int j = f & 7, l = (f >> 3) & 63, s = (f >> 9) & 7;
  const int q = (f >> 12) & 1, w = (f >> 13) & 7, dir = (f >> 16) & 1;
  const int n = 32 * w + 16 * q + (l & 15);
  const int k = 32 * s + 8 * (l >> 4) + j;
  const float* W = dir ? Wbw : Wfw;
  ((unsigned short*)(ws + OFF_JF))[f] = f2bf(W[(size_t)(300 + k) * 1024 + 256 + n] * TWO_L2E);
}

// ---------------- i/f/o W_h fragments (fp8 e4m3, x -log2e*32) ----------------
__global__ __launch_bounds__(512) void k_ifofrag(const float* __restrict__ Wfw, const float* __restrict__ Wbw,
                                                 char* __restrict__ ws) {
  const int f = blockIdx.x * 512 + threadIdx.x;
  const int g3 = f >> 17;
  const int r = f & 131071;
  const int j = r & 7, l = (r >> 3) & 63, s = (r >> 9) & 7;
  const int q = (r >> 12) & 1, w = (r >> 13) & 7, dir = (r >> 16) & 1;
  const int gate = (g3 == 0) ? 0 : ((g3 == 1) ? 2 : 3);
  const int n = 32 * w + 16 * q + (l & 15);
  const int k = 32 * s + 8 * (l >> 4) + j;
  const float* W = dir ? Wbw : Wfw;
  const float v = W[(size_t)(300 + k) * 1024 + gate * 256 + n] * (-L2E * 32.f);
  const int pk = __builtin_amdgcn_cvt_pk_fp8_f32(v, v, 0, false);
  ((unsigned char*)(ws + OFF_IFOF))[f] = (unsigned char)(pk & 0xFF);
}

// ---------------- zE = emb_pad @ WcatT^T + bias (scaled) ----------------
__global__ __launch_bounds__(512) void k_zegemm(char* __restrict__ ws, const float* __restrict__ bfw,
                                                const float* __restrict__ bbw) {
  const int tid = threadIdx.x;
  const int l = tid & 63, w = tid >> 6;
  const int l15 = l & 15, lq = l >> 4;
  const int wr = w >> 2, wc = w & 3;
  const int mbase = blockIdx.x * 128;
  const int nbase = blockIdx.y * 256;
  __shared__ char lds[24576];
  const unsigned short* Ab = (const unsigned short*)(ws + OFF_EMBP);
  const unsigned short* Bb = (const unsigned short*)(ws + OFF_WCT);
  unsigned short* Cb = (unsigned short*)(ws + OFF_ZE);
  const f32x4 zero4 = {0.f, 0.f, 0.f, 0.f};
  f32x4 acc[4][4];
  #pragma unroll
  for (int a = 0; a < 4; ++a)
    #pragma unroll
    for (int b = 0; b < 4; ++b) acc[a][b] = zero4;

  for (int kk = 0; kk < 320; kk += 32) {
    if (kk) __syncthreads();
    {
      const int row = tid >> 2, sl = tid & 3;
      const int gm = mbase + row;
      s16x8 v = {0, 0, 0, 0, 0, 0, 0, 0};
      if (gm < V_N) v = *(const s16x8*)(Ab + (size_t)gm * 320 + kk + sl * 8);
      *(s16x8*)(lds + row * 64 + ((sl ^ ((row >> 1) & 3)) << 4)) = v;
    }
    {
      const int col = tid >> 1, hf = tid & 1;
      #pragma unroll
      for (int ss = 0; ss < 2; ++ss) {
        const int sl = 2 * hf + ss;
        s16x8 v = *(const s16x8*)(Bb + (size_t)(nbase + col) * 320 + kk + sl * 8);
        *(s16x8*)(lds + 8192 + col * 64 + ((sl ^ ((col >> 1) & 3)) << 4)) = v;
      }
    }
    __syncthreads();
    s16x8 af[4], bfr[4];
    #pragma unroll
    for (int mi = 0; mi < 4; ++mi) {
      const int row = 64 * wr + 16 * mi + l15;
      af[mi] = *(const s16x8*)(lds + row * 64 + ((lq ^ ((row >> 1) & 3)) << 4));
    }
    #pragma unroll
    for (int ni = 0; ni < 4; ++ni) {
      const int col = 64 * wc + 16 * ni + l15;
      bfr[ni] = *(const s16x8*)(lds + 8192 + col * 64 + ((lq ^ ((col >> 1) & 3)) << 4));
    }
    #pragma unroll
    for (int mi = 0; mi < 4; ++mi)
      #pragma unroll
      for (int ni = 0; ni < 4; ++ni)
        acc[mi][ni] = mfma_bf16f(af[mi], bfr[ni], acc[mi][ni]);
  }
  float bcol[4];
  #pragma unroll
  for (int ni = 0; ni < 4; ++ni) {
    const int colp = nbase + 64 * wc + 16 * ni + l15;
    const int dirc = colp >> 10, pp = colp & 1023;
    const int gt = pp & 3;
    const int n = ((pp >> 7) << 5) + ((pp >> 2) & 31);
    const float* bsel = dirc ? bbw : bfw;
    const float bv = bsel[gt * 256 + n];
    bcol[ni] = (gt == 1) ? bv * TWO_L2E : -(bv + ((gt == 2) ? 1.f : 0.f)) * L2E;
  }
  #pragma unroll
  for (int mi = 0; mi < 4; ++mi)
    #pragma unroll
    for (int ni = 0; ni < 4; ++ni)
      #pragma unroll
      for (int rr = 0; rr < 4; ++rr) {
        const int gr = mbase + 64 * wr + 16 * mi + 4 * lq + rr;
        if (gr < V_N)
          Cb[(size_t)gr * 2048 + nbase + 64 * wc + 16 * ni + l15] = f2bf(acc[mi][ni][rr] + bcol[ni]);
      }
}

// ---------------- bidirectional LSTM recurrence (8 waves, q-sequential, WJ1 in LDS) ----------------
// R12 structure + bf16 bit-trick unpack/repack (G-phase VALU trim).
// LDS: offs u32[512][16] 32K | h bf16 dbuf 2x8K | h fp8 dbuf 2x4K | WJ1 [8w][8s][64l]x16B 64K
#define L_OFFS 0
#define L_HB0  32768
#define L_HB1  40960
#define L_HF0  49152
#define L_HF1  53248
#define L_WJ1  57344
#define L_LDS  122880

#define LSTM_STEP(CUR, S)                                                          \
  do {                                                                             \
    const int tt_ = dir ? (T_N - 1 - (S)) : (S);                                   \
    const char* hb_  = lds + ((CUR) ? L_HB1 : L_HB0);                              \
    const char* hf8_ = lds + ((CUR) ? L_HF1 : L_HF0);                              \
    char* hbn_  = lds + ((CUR) ? L_HB0 : L_HB1);                                   \
    char* hf8n_ = lds + ((CUR) ? L_HF0 : L_HF1);                                   \
    _Pragma("unroll")                                                              \
    for (int q = 0; q < 2; ++q) {                                                  \
      f32x4 aI_ = zero4, aJ_ = zero4, aF_ = zero4, aO_ = zero4;                    \
      _Pragma("unroll")                                                            \
      for (int s8 = 0; s8 < 8; ++s8) {                                             \
        const int slot = 4 * s8 + lq;                                              \
        s16x8 abf = *(const s16x8*)(hb_ + l15 * 512 + ((slot ^ l15) << 4));        \
        long af8  = *(const long*)(hf8_ + l15 * 256 + ((slot ^ l15) << 3));        \
        s16x8 bj = (q == 0) ? WJ0[s8] : *(const s16x8*)(wj1b + (s8 << 10));        \
        aJ_ = mfma_bf16f(abf, bj, aJ_);                                            \
        aI_ = mfma_fp8f(af8, WIFO[0][q][s8], aI_);                                 \
        aF_ = mfma_fp8f(af8, WIFO[1][q][s8], aF_);                                 \
        aO_ = mfma_fp8f(af8, WIFO[2][q][s8], aO_);                                 \
      }                                                                            \
      _Pragma("unroll")                                                            \
      for (int r = 0; r < 4; ++r) {                                                \
        const int row = 4 * lq + r;                                                \
        const bool m_ = (tt_ < lenr[r]);                                           \
        const u32x2 zraw = zxr[q][r];                                              \
        const float zxi = asf(zraw.x << 16);                                       \
        const float zxj = asf(zraw.x & 0xFFFF0000u);                               \
        const float zxf = asf(zraw.y << 16);                                       \
        const float zxo = asf(zraw.y & 0xFFFF0000u);                               \
        const float zi = __builtin_fmaf(aI_[r], 0.0009765625f, zxi);               \
        const float zj = aJ_[r] + zxj;                                             \
        const float zf = __builtin_fmaf(aF_[r], 0.0009765625f, zxf);               \
        const float zo = __builtin_fmaf(aO_[r], 0.0009765625f, zxo);               \
        const float vi = EXP2F(zi);                                                \
        const float uj = EXP2F(zj);                                                \
        const float vf = EXP2F(zf);                                                \
        const float sfg = RCPF(1.f + vf);                                          \
        const float tij = (uj - 1.f) * RCPF((1.f + vi) * (1.f + uj));              \
        const float cn = __builtin_fmaf(cst[r + 4 * q], sfg, tij);                 \
        const float cne = fminf(cn, 30.f);                                         \
        const float wv = EXP2F(cne * TWO_L2E);                                     \
        const float xo = EXP2F(zo);                                                \
        const float hn = (wv - 1.f) * RCPF((wv + 1.f) * (1.f + xo));               \
        cst[r + 4 * q] = m_ ? cn : cst[r + 4 * q];                                 \
        const float hold = asf(q ? (hp[r] & 0xFFFF0000u) : (hp[r] << 16));         \
        const float hv = m_ ? hn : hold;                                           \
        unsigned int pkb;                                                          \
        asm("v_cvt_pk_bf16_f32 %0, %1, %2" : "=v"(pkb) : "v"(hv), "v"(hv));        \
        hp[r] = q ? ((hp[r] & 0xFFFFu) | (pkb & 0xFFFF0000u))                      \
                  : ((hp[r] & 0xFFFF0000u) | (pkb & 0xFFFFu));                     \
        const int n0q = 32 * w + 16 * q + l15;                                     \
        *(unsigned short*)(hbn_ + row * 512 + (((n0q >> 3) ^ row) << 4) + ((n0q & 7) << 1)) = (unsigned short)pkb; \
        const int pk8 = __builtin_amdgcn_cvt_pk_fp8_f32(hv * 32.f, hv * 32.f, 0, false); \
        hf8n_[row * 256 + (((n0q >> 3) ^ row) << 3) + (n0q & 7)] = (char)(pk8 & 0xFF); \
      }                                                                            \
      if ((S) + 1 < T_N) { /* refill zxr[q] for step S+1 (just freed; ample cover) */ \
        const unsigned int* opn_ = (const unsigned int*)(lds + L_OFFS) + ((S) + 1) * 16 + 4 * lq; \
        const u32x4 off4 = *(const u32x4*)(opn_);                                  \
        _Pragma("unroll")                                                          \
        for (int r = 0; r < 4; ++r) {                                              \
          const char* gb = zeb + off4[r] + (w << 8) + (q << 7) + (l15 << 3);       \
          zxr[q][r] = *(const u32x2*)(gb);                                         \
        }                                                                          \
      }                                                                            \
      __builtin_amdgcn_sched_barrier(0);  /* keep q-phases separate: 16-AGPR acc live range */ \
    }                                                                              \
    asm volatile("s_waitcnt lgkmcnt(0)" ::: "memory");                             \
    __builtin_amdgcn_s_barrier();                                                  \
    asm volatile("" ::: "memory");                                                 \
  } while (0)

__global__ __launch_bounds__(512, 1) void k_lstm(const int* __restrict__ ids, char* __restrict__ ws) {
  const int tid = threadIdx.x;
  const int l = tid & 63, w = tid >> 6;
  const int l15 = l & 15, lq = l >> 4;
  const int bid = blockIdx.x;
  const int dir = bid & 1, g = bid >> 1;

  __shared__ char lds[L_LDS];

  { // one-time: zE byte-offset table offs[s][row] (dir-reversed, dir-half folded)
    unsigned int* op = (unsigned int*)(lds + L_OFFS);
    const int row = tid >> 5, tb = (tid & 31) << 4;
    const int base = (g * 16 + row) * T_N;
    #pragma unroll 4
    for (int i = 0; i < 16; ++i) {
      const int t = tb + i;
      const int id = ids[base + t];
      const int sidx = dir ? (T_N - 1 - t) : t;
      op[sidx * 16 + row] = (unsigned int)(id * 4096 + dir * 2048);
    }
  }
  { // zero h buf0
    unsigned int* p = (unsigned int*)(lds + L_HB0);
    #pragma unroll
    for (int i = 0; i < 4; ++i) p[tid + 512 * i] = 0u;
    unsigned int* p2 = (unsigned int*)(lds + L_HF0);
    #pragma unroll
    for (int i = 0; i < 2; ++i) p2[tid + 512 * i] = 0u;
  }
  { // stage q=1 j-weights into per-wave-private LDS [w][s8][l]x16B (wave stages its own region)
    const char* jf = ws + OFF_JF;
    #pragma unroll
    for (int s = 0; s < 8; ++s) {
      s16x8 v = *(const s16x8*)(jf + (size_t)((((dir * 8 + w) * 2 + 1) * 8 + s) * 64 + l) * 16);
      *(s16x8*)(lds + L_WJ1 + (w << 13) + (s << 10) + (l << 4)) = v;
    }
  }

  // resident weight fragments: WJ0 32 + WIFO 96 = 128 regs (exactly the AGPR half)
  s16x8 WJ0[8];
  long WIFO[3][2][8];
  {
    const char* jf = ws + OFF_JF;
    #pragma unroll
    for (int s = 0; s < 8; ++s)
      WJ0[s] = *(const s16x8*)(jf + (size_t)((((dir * 8 + w) * 2 + 0) * 8 + s) * 64 + l) * 16);
    const char* ff = ws + OFF_IFOF;
    #pragma unroll
    for (int g3 = 0; g3 < 3; ++g3)
      #pragma unroll
      for (int q = 0; q < 2; ++q)
        #pragma unroll
        for (int s = 0; s < 8; ++s)
          WIFO[g3][q][s] = *(const long*)(ff + g3 * 131072 + (dir << 16) + (w << 13) + (q << 12) + (s << 9) + (l << 3));
  }
  int lenr[4];
  {
    const int* lp = (const int*)(ws + OFF_LEN);
    #pragma unroll
    for (int r = 0; r < 4; ++r) lenr[r] = lp[g * 16 + 4 * lq + r];
  }
  float cst[8] = {0, 0, 0, 0, 0, 0, 0, 0};
  unsigned int hp[4] = {0, 0, 0, 0};      // packed bf16 h (q0 | q1<<16) per r
  const char* zeb = ws + OFF_ZE;
  const char* wj1b = lds + L_WJ1 + (w << 13) + (l << 4);   // per-thread q1 j-frag base
  const f32x4 zero4 = {0.f, 0.f, 0.f, 0.f};
  u32x2 zxr[2][4];                         // this lane's zx slice for the current step

  __syncthreads();                 // offs + h0 + WJ1 ready

  { // prologue: zx for step 0 (both q halves)
    const unsigned int* op_ = (const unsigned int*)(lds + L_OFFS);
    const u32x4 off4 = *(const u32x4*)(op_ + 4 * lq);
    #pragma unroll
    for (int r = 0; r < 4; ++r) {
      const char* gb = zeb + off4[r] + (w << 8) + (l15 << 3);
      zxr[0][r] = *(const u32x2*)(gb);
      zxr[1][r] = *(const u32x2*)(gb + 128);
    }
  }

  for (int s = 0; s < T_N; s += 2) {
    LSTM_STEP(0, s);
    LSTM_STEP(1, s + 1);
  }

  float* hout = (float*)(ws + OFF_HFIN) + (size_t)dir * 65536;
  #pragma unroll
  for (int r = 0; r < 4; ++r) {
    const int grow = (g * 16 + 4 * lq + r) * 256 + 32 * w + l15;
    hout[grow]      = bf2f(hp[r] & 0xFFFFu);
    hout[grow + 16] = bf2f(hp[r] >> 16);
  }
}

// ---------------- output projection ----------------
__global__ __launch_bounds__(64) void k_scores(const char* __restrict__ ws, const float* __restrict__ Wout,
                                               const float* __restrict__ bout, float* __restrict__ out) {
  const int row = blockIdx.x, l = threadIdx.x;
  const float* h1 = (const float*)(ws + OFF_HFIN);
  const float* h2 = h1 + 65536;
  float a0 = 0.f, a1 = 0.f;
  #pragma unroll
  for (int j = 0; j < 8; ++j) {
    const int k = l + 64 * j;
    const float v = (k < 256) ? h1[row * 256 + k] : h2[row * 256 + (k - 256)];
    a0 += v * Wout[2 * k];
    a1 += v * Wout[2 * k + 1];
  }
  #pragma unroll
  for (int off = 32; off; off >>= 1) {
    a0 += __shfl_down(a0, off);
    a1 += __shfl_down(a1, off);
  }
  if (l == 0) {
    out[2 * row] = a0 + bout[0];
    out[2 * row + 1] = a1 + bout[1];
  }
}

__global__ void k_sentinel(float* out) { out[threadIdx.x] = -12345.f; }

extern "C" void kernel_launch(void* const* d_in, const int* in_sizes, int n_in,
                              void* d_out, int out_size, void* d_ws, size_t ws_size,
                              hipStream_t stream) {
  const int* ids = (const int*)d_in[0];
  const float* emb = (const float*)d_in[1];
  const float* Wfw = (const float*)d_in[2];
  const float* bfw = (const float*)d_in[3];
  const float* Wbw = (const float*)d_in[4];
  const float* bbw = (const float*)d_in[5];
  const float* Wout = (const float*)d_in[6];
  const float* bout = (const float*)d_in[7];
  float* out = (float*)d_out;
  char* ws = (char*)d_ws;
  (void)in_sizes; (void)n_in; (void)out_size;

  if (ws_size < WS_NEED) {
    k_sentinel<<<dim3(1), dim3(512), 0, stream>>>(out);
    return;
  }
  k_lengths<<<dim3(256), dim3(64), 0, stream>>>(ids, ws);
  k_embpad<<<dim3(50000), dim3(320), 0, stream>>>(emb, ws);
  k_wcat<<<dim3(2048), dim3(320), 0, stream>>>(Wfw, Wbw, ws);
  k_jfrag<<<dim3(256), dim3(512), 0, stream>>>(Wfw, Wbw, ws);
  k_ifofrag<<<dim3(768), dim3(512), 0, stream>>>(Wfw, Wbw, ws);
  k_zegemm<<<dim3(391, 8), dim3(512), 0, stream>>>(ws, bfw, bbw);
  k_lstm<<<dim3(32), dim3(512), 0, stream>>>(ids, ws);
  k_scores<<<dim3(256), dim3(64), 0, stream>>>(ws, Wout, bout, out);
}